// Round 1
// baseline (1320.684 us; speedup 1.0000x reference)
//
#include <hip/hip_runtime.h>

// out[b,o] = sum_{i<64, l<32} obs[b,i,l,o] * ctx[b, 31-l, i]
// B=2048, R=32, O=64, fp32. Memory-bound: obs = 1 GiB streamed once.

#define BB 2048
#define RR 32
#define OO 64

__global__ __launch_bounds__(256) void cnnkf_kernel(
    const float* __restrict__ ctx,   // [B, R, O]
    const float* __restrict__ obs,   // [B, O, R, O]
    float* __restrict__ out)         // [B, O]
{
    __shared__ float  lds_ctx[RR * OO];   // 8 KB: ctx[b] staged
    __shared__ float4 lds_red[256];       // 4 KB: reduction

    const int b  = blockIdx.x;
    const int t  = threadIdx.x;
    const int og = t & 15;   // float4 group along o: covers o = 4*og .. 4*og+3
    const int s  = t >> 4;   // slice 0..15 over the 2048 (i,l) pairs

    // Stage ctx[b] (32x64 floats) into LDS, coalesced float4.
    const float4* ctx4 = reinterpret_cast<const float4*>(ctx + (size_t)b * (RR * OO));
    float4* lds4 = reinterpret_cast<float4*>(lds_ctx);
    lds4[t]       = ctx4[t];
    lds4[t + 256] = ctx4[t + 256];
    __syncthreads();

    // p = i*32 + l indexes the (i,l) pair; this thread handles p in [s*128, s*128+128).
    // obs[b,i,l, 4*og..4*og+3] is float4 element (p*16 + og) of obs[b].
    const float4* obs4 = reinterpret_cast<const float4*>(obs + (size_t)b * (OO * RR * OO));
    float4 acc = {0.f, 0.f, 0.f, 0.f};
    const int pbase = s * 128;

    #pragma unroll 8
    for (int k = 0; k < 128; ++k) {
        const int p = pbase + k;
        const int i = p >> 5;          // i = s*4 + (k>>5)
        const int l = p & 31;          // l = k & 31 (s*128 is a multiple of 32)
        const float c = lds_ctx[(31 - l) * OO + i];  // 4 distinct addrs/wave, 4 banks apart
        const float4 v = obs4[p * 16 + og];          // 4 x 256B coalesced segments / wave
        acc.x += v.x * c;
        acc.y += v.y * c;
        acc.z += v.z * c;
        acc.w += v.w * c;
    }

    lds_red[t] = acc;
    __syncthreads();

    // Tree-reduce over the 16 slices (stride stays a multiple of 16 so og matches).
    for (int stride = 128; stride >= 16; stride >>= 1) {
        if (t < stride) {
            float4 a = lds_red[t];
            const float4 c = lds_red[t + stride];
            a.x += c.x; a.y += c.y; a.z += c.z; a.w += c.w;
            lds_red[t] = a;
        }
        __syncthreads();
    }

    if (t < 16) {
        reinterpret_cast<float4*>(out + (size_t)b * OO)[t] = lds_red[t];
    }
}

extern "C" void kernel_launch(void* const* d_in, const int* in_sizes, int n_in,
                              void* d_out, int out_size, void* d_ws, size_t ws_size,
                              hipStream_t stream) {
    const float* ctx = (const float*)d_in[0];  // context [2048, 32, 64]
    const float* obs = (const float*)d_in[1];  // observation_IR [2048, 64, 32, 64]
    float* out = (float*)d_out;                // [2048, 64]
    cnnkf_kernel<<<dim3(BB), dim3(256), 0, stream>>>(ctx, obs, out);
}